// Round 1
// baseline (152.505 us; speedup 1.0000x reference)
//
#include <hip/hip_runtime.h>
#include <hip/hip_bf16.h>
#include <stdint.h>

#define NROWS 8192
#define NDIM  512
#define MARGIN 0.3f

typedef __attribute__((ext_vector_type(4))) float floatx4;
typedef __attribute__((ext_vector_type(8))) short shortx8;

__device__ inline unsigned short f32_to_bf16_bits(float x) {
  union { float f; unsigned int u; } v; v.f = x;
  unsigned int r = v.u + 0x7FFFu + ((v.u >> 16) & 1u);  // round-to-nearest-even
  return (unsigned short)(r >> 16);
}

// fp32 [N*D] -> bf16 bits [N*D], vectorized 4-wide
__global__ void convert_kernel(const float4* __restrict__ in, ushort4* __restrict__ out) {
  int i = blockIdx.x * blockDim.x + threadIdx.x;
  float4 f = in[i];
  ushort4 o;
  o.x = f32_to_bf16_bits(f.x);
  o.y = f32_to_bf16_bits(f.y);
  o.z = f32_to_bf16_bits(f.z);
  o.w = f32_to_bf16_bits(f.w);
  out[i] = o;
}

__device__ inline void gload_lds16(const void* g, void* l) {
  __builtin_amdgcn_global_load_lds(
      (const __attribute__((address_space(1))) unsigned int*)g,
      (__attribute__((address_space(3))) unsigned int*)l, 16, 0, 0);
}

// Fused sim = X·X^T tile GEMM (bf16 MFMA) + contrastive-loss epilogue + reduction.
// Only upper-triangular 128x128 blocks are computed; off-diagonal blocks count 2x.
__launch_bounds__(256)
__global__ void loss_kernel(const ushort* __restrict__ Xb, const int* __restrict__ tg,
                            float* __restrict__ out) {
  __shared__ ushort As[128 * 64];   // [row][k] bf16, 16 KB
  __shared__ ushort Bs[128 * 64];   // [col][k] bf16, 16 KB
  __shared__ int tRow[128];
  __shared__ int tCol[128];
  __shared__ float wsum[4];

  // decode linear block id -> (bi, bj), bj >= bi (row-major upper triangle)
  int t = blockIdx.x;
  int bi = 0, len = 64;
  while (t >= len) { t -= len; len--; bi++; }
  int bj = bi + t;

  const int tid  = threadIdx.x;
  const int lane = tid & 63;
  const int w    = tid >> 6;       // 4 waves
  const int wm   = w >> 1, wn = w & 1;  // 2x2 wave grid, 64x64 per wave
  const int quad = lane >> 4;
  const int l16  = lane & 15;

  const int rowBase = bi * 128;
  const int colBase = bj * 128;

  if (tid < 128) tRow[tid] = tg[rowBase + tid];
  else           tCol[tid - 128] = tg[colBase + tid - 128];

  floatx4 acc[4][4];
#pragma unroll
  for (int a = 0; a < 4; a++)
#pragma unroll
    for (int b = 0; b < 4; b++) acc[a][b] = (floatx4)(0.f);

  for (int k0 = 0; k0 < NDIM; k0 += 64) {
    __syncthreads();  // all waves done reading previous tile
    // stage A (128x64) and B (128x64): 16 chunks of 1 KiB each, 4 per wave per matrix
#pragma unroll
    for (int it = 0; it < 4; it++) {
      int chunk = it * 4 + w;              // 0..15, 512 elems (8 rows) each
      int eo = chunk * 512 + lane * 8;     // element offset inside tile
      int r = eo >> 6, c = eo & 63;
      gload_lds16(Xb + (size_t)(rowBase + r) * NDIM + k0 + c, As + chunk * 512);
      gload_lds16(Xb + (size_t)(colBase + r) * NDIM + k0 + c, Bs + chunk * 512);
    }
    __syncthreads();  // staging complete (compiler drains vmcnt before barrier)

#pragma unroll
    for (int kk = 0; kk < 64; kk += 32) {
      shortx8 a[4], b[4];
      const int kcol = kk + quad * 8;
#pragma unroll
      for (int mt = 0; mt < 4; mt++)
        a[mt] = *(const shortx8*)(As + (wm * 64 + mt * 16 + l16) * 64 + kcol);
#pragma unroll
      for (int nt = 0; nt < 4; nt++)
        b[nt] = *(const shortx8*)(Bs + (wn * 64 + nt * 16 + l16) * 64 + kcol);
#pragma unroll
      for (int mt = 0; mt < 4; mt++)
#pragma unroll
        for (int nt = 0; nt < 4; nt++)
          acc[mt][nt] = __builtin_amdgcn_mfma_f32_16x16x32_bf16(a[mt], b[nt], acc[mt][nt], 0, 0, 0);
    }
  }

  // Epilogue: C/D layout col=lane&15, row=quad*4+reg  [measured m89/m91]
  float lsum = 0.f;
  const bool diag = (bi == bj);
#pragma unroll
  for (int mt = 0; mt < 4; mt++) {
    const int rloc = wm * 64 + mt * 16 + quad * 4;
#pragma unroll
    for (int nt = 0; nt < 4; nt++) {
      const int cloc = wn * 64 + nt * 16 + l16;
      const int tc = tCol[cloc];
      const int col = colBase + cloc;
#pragma unroll
      for (int r = 0; r < 4; r++) {
        const float s = acc[mt][nt][r];
        const int tr = tRow[rloc + r];
        float c = (tr == tc) ? ((s < 1.f) ? 1.f - s : 0.f)
                             : ((s > MARGIN) ? s : 0.f);
        float wgt;
        if (!diag) {
          wgt = 2.f;
        } else {
          const int row = rowBase + rloc + r;
          wgt = (row < col) ? 2.f : ((row == col) ? 1.f : 0.f);
        }
        lsum += wgt * c;
      }
    }
  }

  // wave reduce (64 lanes), then block reduce, one atomic per block
#pragma unroll
  for (int off = 32; off > 0; off >>= 1) lsum += __shfl_down(lsum, off, 64);
  if (lane == 0) wsum[w] = lsum;
  __syncthreads();
  if (tid == 0) {
    float tot = (wsum[0] + wsum[1] + wsum[2] + wsum[3]) * (1.0f / NROWS);
    atomicAdd(out, tot);
  }
}

extern "C" void kernel_launch(void* const* d_in, const int* in_sizes, int n_in,
                              void* d_out, int out_size, void* d_ws, size_t ws_size,
                              hipStream_t stream) {
  const float* x = (const float*)d_in[0];
  const int* tg  = (const int*)d_in[1];
  float* out     = (float*)d_out;
  ushort* xb     = (ushort*)d_ws;   // bf16 copy of X, 8 MiB

  hipMemsetAsync(d_out, 0, sizeof(float), stream);   // harness poisons d_out with 0xAA
  convert_kernel<<<(NROWS * NDIM / 4) / 256, 256, 0, stream>>>((const float4*)x, (ushort4*)xb);
  loss_kernel<<<64 * 65 / 2, 256, 0, stream>>>(xb, tg, out);
}

// Round 2
// 139.483 us; speedup vs baseline: 1.0934x; 1.0934x over previous
//
#include <hip/hip_runtime.h>
#include <hip/hip_bf16.h>
#include <stdint.h>

#define NROWS 8192
#define NDIM  512
#define MARGIN 0.3f
#define NB    64          // 8192 / 128 row-blocks
#define NT    (NB*(NB+1)/2)

typedef __attribute__((ext_vector_type(4))) float floatx4;
typedef __attribute__((ext_vector_type(8))) short shortx8;

__device__ inline unsigned short f32_to_bf16_bits(float x) {
  union { float f; unsigned int u; } v; v.f = x;
  unsigned int r = v.u + 0x7FFFu + ((v.u >> 16) & 1u);  // RNE
  return (unsigned short)(r >> 16);
}

// fp32 -> bf16, 16 floats per thread (64B read / 32B write per lane)
__global__ void convert_kernel(const float4* __restrict__ in, shortx8* __restrict__ out,
                               float* __restrict__ loss_out) {
  int i = blockIdx.x * blockDim.x + threadIdx.x;
  if (i == 0) loss_out[0] = 0.f;          // d_out is poisoned each replay
  float4 f[4];
#pragma unroll
  for (int j = 0; j < 4; j++) f[j] = in[i * 4 + j];
  shortx8 o0, o1;
#pragma unroll
  for (int j = 0; j < 2; j++) {
    o0[j*4+0] = (short)f32_to_bf16_bits(f[j].x);
    o0[j*4+1] = (short)f32_to_bf16_bits(f[j].y);
    o0[j*4+2] = (short)f32_to_bf16_bits(f[j].z);
    o0[j*4+3] = (short)f32_to_bf16_bits(f[j].w);
    o1[j*4+0] = (short)f32_to_bf16_bits(f[j+2].x);
    o1[j*4+1] = (short)f32_to_bf16_bits(f[j+2].y);
    o1[j*4+2] = (short)f32_to_bf16_bits(f[j+2].z);
    o1[j*4+3] = (short)f32_to_bf16_bits(f[j+2].w);
  }
  out[i * 2 + 0] = o0;
  out[i * 2 + 1] = o1;
}

__device__ inline void gload_lds16(const void* g, void* l) {
  __builtin_amdgcn_global_load_lds(
      (const __attribute__((address_space(1))) unsigned int*)g,
      (__attribute__((address_space(3))) unsigned int*)l, 16, 0, 0);
}

// sim = X·X^T upper-triangular 128x128 blocks, bf16 MFMA, double-buffered LDS,
// XOR-swizzled LDS layout (the swizzle permutes the per-lane GLOBAL address of
// global_load_lds; LDS side is forced linear base+lane*16).
__launch_bounds__(256)
__global__ void loss_kernel(const ushort* __restrict__ Xb, const int* __restrict__ tg,
                            float* __restrict__ out) {
  __shared__ ushort As[2][128 * 64];   // 16 KB each
  __shared__ ushort Bs[2][128 * 64];
  __shared__ int tRow[128];
  __shared__ int tCol[128];
  __shared__ float wsum[4];

  // closed-form triangular decode: row bi occupies [s(bi), s(bi)+64-bi), s(bi)=64bi - bi(bi-1)/2
  int t = blockIdx.x;
  int bi = (int)((129.0f - sqrtf((float)(16641 - 8 * t))) * 0.5f);
  if (bi < 0) bi = 0; if (bi > 63) bi = 63;
  while (bi > 0 && (64 * bi - (bi * (bi - 1)) / 2) > t) bi--;
  while (bi < 63 && (64 * (bi + 1) - ((bi + 1) * bi) / 2) <= t) bi++;
  int bj = bi + (t - (64 * bi - (bi * (bi - 1)) / 2));

  const int tid  = threadIdx.x;
  const int lane = tid & 63;
  const int w    = tid >> 6;
  const int wm   = w >> 1, wn = w & 1;   // 2x2 waves, 64x64 each
  const int quad = lane >> 4;
  const int l16  = lane & 15;

  const int rowBase = bi * 128;
  const int colBase = bj * 128;

  // staging geometry: 16 chunks of 1 KiB per 128x64 tile; chunk = 8 rows.
  // lane covers LDS elems [chunk*512 + lane*8); logical (r, c16) with
  // r = chunk*8 + lane/8, stored 16B-chunk index (lane&7) = c16 ^ (r&7).
  const int sr  = lane >> 3;             // row within chunk
  const int sc  = lane & 7;              // LDS 16B slot within row

#define STAGE(K0, BUF)                                                          \
  do {                                                                          \
    _Pragma("unroll")                                                           \
    for (int it = 0; it < 4; it++) {                                            \
      int chunk = it * 4 + w;                                                   \
      int r = (chunk << 3) + sr;                                                \
      int cg = sc ^ (r & 7);                                                    \
      gload_lds16(Xb + (size_t)(rowBase + r) * NDIM + (K0) + cg * 8,            \
                  &As[BUF][chunk * 512]);                                       \
      gload_lds16(Xb + (size_t)(colBase + r) * NDIM + (K0) + cg * 8,            \
                  &Bs[BUF][chunk * 512]);                                       \
    }                                                                           \
  } while (0)

  STAGE(0, 0);
  if (tid < 128) tRow[tid] = tg[rowBase + tid];
  else           tCol[tid - 128] = tg[colBase + tid - 128];

  floatx4 acc[4][4];
#pragma unroll
  for (int a = 0; a < 4; a++)
#pragma unroll
    for (int b = 0; b < 4; b++) acc[a][b] = (floatx4)(0.f);

  __syncthreads();   // tile 0 staged

#pragma unroll
  for (int kt = 0; kt < 8; kt++) {
    const int buf = kt & 1;
    if (kt < 7) STAGE((kt + 1) * 64, buf ^ 1);   // prefetch flies under compute

#pragma unroll
    for (int kk = 0; kk < 2; kk++) {
      shortx8 a[4], b[4];
      const int kc = kk * 4 + quad;              // logical 16B chunk 0..7
#pragma unroll
      for (int mt = 0; mt < 4; mt++) {
        const int row = wm * 64 + mt * 16 + l16;
        a[mt] = *(const shortx8*)(&As[buf][row * 64 + ((kc ^ (row & 7)) << 3)]);
      }
#pragma unroll
      for (int nt = 0; nt < 4; nt++) {
        const int row = wn * 64 + nt * 16 + l16;
        b[nt] = *(const shortx8*)(&Bs[buf][row * 64 + ((kc ^ (row & 7)) << 3)]);
      }
#pragma unroll
      for (int mt = 0; mt < 4; mt++)
#pragma unroll
        for (int nt = 0; nt < 4; nt++)
          acc[mt][nt] = __builtin_amdgcn_mfma_f32_16x16x32_bf16(a[mt], b[nt], acc[mt][nt], 0, 0, 0);
    }
    __syncthreads();   // drains prefetch vmcnt + protects buf reuse
  }

  // Epilogue: C/D layout col=lane&15, row=quad*4+reg
  float lsum = 0.f;
  const bool diag = (bi == bj);
#pragma unroll
  for (int mt = 0; mt < 4; mt++) {
    const int rloc = wm * 64 + mt * 16 + quad * 4;
#pragma unroll
    for (int nt = 0; nt < 4; nt++) {
      const int cloc = wn * 64 + nt * 16 + l16;
      const int tc = tCol[cloc];
      const int col = colBase + cloc;
#pragma unroll
      for (int r = 0; r < 4; r++) {
        const float s = acc[mt][nt][r];
        const int tr = tRow[rloc + r];
        float c = (tr == tc) ? ((s < 1.f) ? 1.f - s : 0.f)
                             : ((s > MARGIN) ? s : 0.f);
        float wgt;
        if (!diag) {
          wgt = 2.f;
        } else {
          const int row = rowBase + rloc + r;
          wgt = (row < col) ? 2.f : ((row == col) ? 1.f : 0.f);
        }
        lsum += wgt * c;
      }
    }
  }

#pragma unroll
  for (int off = 32; off > 0; off >>= 1) lsum += __shfl_down(lsum, off, 64);
  if (lane == 0) wsum[w] = lsum;
  __syncthreads();
  if (tid == 0) {
    float tot = (wsum[0] + wsum[1] + wsum[2] + wsum[3]) * (1.0f / NROWS);
    atomicAdd(out, tot);
  }
}

extern "C" void kernel_launch(void* const* d_in, const int* in_sizes, int n_in,
                              void* d_out, int out_size, void* d_ws, size_t ws_size,
                              hipStream_t stream) {
  const float* x = (const float*)d_in[0];
  const int* tg  = (const int*)d_in[1];
  float* out     = (float*)d_out;
  ushort* xb     = (ushort*)d_ws;   // bf16 X, 8 MiB

  convert_kernel<<<(NROWS * NDIM / 16) / 256, 256, 0, stream>>>(
      (const float4*)x, (shortx8*)xb, out);
  loss_kernel<<<NT, 256, 0, stream>>>(xb, tg, out);
}